// Round 4
// baseline (547.988 us; speedup 1.0000x reference)
//
#include <hip/hip_runtime.h>
#include <hip/hip_fp16.h>

#define NN 100000
#define EE 3200000
#define SLOPE 0.2f

#define SBN 32                               // dst-nodes per sub-bucket
constexpr int NSB = NN / SBN;                // 3125 sub-buckets (exact)
#define NSBP 3328                            // padded to 13*256 for the block scan
#define CAPS 1344                            // per-sub-bucket cap: mean 1024 + 10 sigma
#define EPB 1792                             // edges per bucket-sort block (LDS fit)
constexpr int NBB = (EE + EPB - 1) / EPB;    // 1786 sort blocks
constexpr int NBT = (NN + 255) / 256;        // 391 node blocks
#define SUBN 1344                            // LDS edge cap per sub-bucket (= CAPS)

// ------------- fat kernel: 32-node-bucket counting-sort (blocks 0..NBB) + h1 ---------
// record = {src | (dst&31)<<17, edge_attr}; reservation atomic doubles as bucket count
__global__ void k_fat(const int* __restrict__ src, const int* __restrict__ dst,
                      const float* __restrict__ ea, int* __restrict__ cnt,
                      int2* __restrict__ stage,
                      const int* __restrict__ ids, const float* __restrict__ feat,
                      const float* __restrict__ emb, const float* __restrict__ W,
                      const float* __restrict__ avs, const float* __restrict__ avd,
                      __half* __restrict__ h, float* __restrict__ as_,
                      float* __restrict__ ad_) {
    __shared__ int hst[NSBP];
    __shared__ int scl[NSBP];
    __shared__ int gdel[NSBP];
    __shared__ int aux[256];
    __shared__ int2 rec[EPB];
    __shared__ int addr[EPB];
    int t = threadIdx.x;
    if (blockIdx.x < NBB) {
        // ---------- bucket counting sort ----------
        int base = blockIdx.x * EPB;
        int nedge = min(EPB, EE - base);
        for (int i = t; i < NSBP; i += 256) hst[i] = 0;
        __syncthreads();
        int ds[7], ss[7]; float es[7];
#pragma unroll
        for (int j = 0; j < 7; j++) {
            int e = base + j * 256 + t;
            bool v = e < EE;
            ds[j] = v ? dst[e] : -1;
            ss[j] = v ? src[e] : 0;
            es[j] = v ? ea[e] : 0.f;
            if (v) atomicAdd(&hst[ds[j] >> 5], 1);
        }
        __syncthreads();
        // block-wide exclusive scan of 3328 counters (13 per thread)
        int i0 = t * 13;
        int vv[13];
        int tsum = 0;
#pragma unroll
        for (int j = 0; j < 13; j++) { vv[j] = hst[i0 + j]; tsum += vv[j]; }
        aux[t] = tsum;
        __syncthreads();
        for (int off = 1; off < 256; off <<= 1) {
            int x = (t >= off) ? aux[t - off] : 0;
            __syncthreads();
            aux[t] += x;
            __syncthreads();
        }
        int ex = aux[t] - tsum;
#pragma unroll
        for (int j = 0; j < 13; j++) { scl[i0 + j] = ex; ex += vv[j]; }
        __syncthreads();
        for (int i = t; i < NSB; i += 256) {
            int hh = hst[i];
            int g = hh ? atomicAdd(&cnt[i], hh) : 0;
            gdel[i] = (g + i * CAPS) - scl[i];
        }
        __syncthreads();
#pragma unroll
        for (int j = 0; j < 7; j++) {
            if (ds[j] >= 0) {
                int bk = ds[j] >> 5;
                int pos = atomicAdd(&scl[bk], 1);
                int gpos = pos + gdel[bk];
                rec[pos] = make_int2(ss[j] | ((ds[j] & 31) << 17), __float_as_int(es[j]));
                addr[pos] = (gpos - bk * CAPS < CAPS) ? gpos : -1;
            }
        }
        __syncthreads();
        for (int i = t; i < nedge; i += 256) {
            int a = addr[i];
            if (a >= 0) stage[a] = rec[i];
        }
    } else {
        // ---------- h1: x=concat(emb,feat); h=x@W1 (stored fp16); as/ad dots fp32 -----
        int n = (blockIdx.x - NBB) * 256 + t;
        if (n >= NN) return;
        float hv[32];
#pragma unroll
        for (int j = 0; j < 32; j++) hv[j] = 0.f;
        int id = ids[n];
        const float4* e4 = (const float4*)(emb + (size_t)id * 16);
#pragma unroll
        for (int k4 = 0; k4 < 4; k4++) {
            float4 xv = e4[k4];
            const float* wr = W + k4 * 4 * 32;
#pragma unroll
            for (int j = 0; j < 32; j++)
                hv[j] += xv.x * wr[j] + xv.y * wr[32 + j] + xv.z * wr[64 + j] + xv.w * wr[96 + j];
        }
        float f = feat[n];
#pragma unroll
        for (int j = 0; j < 32; j++) hv[j] += f * W[16 * 32 + j];
        float s = 0.f, d = 0.f;
#pragma unroll
        for (int j = 0; j < 32; j++) { s += hv[j] * avs[j]; d += hv[j] * avd[j]; }
        as_[n] = s;
        ad_[n] = d;
        __half2 tmp[16];
#pragma unroll
        for (int q = 0; q < 16; q++) tmp[q] = __floats2half2_rn(hv[2 * q], hv[2 * q + 1]);
        uint4* dst4 = (uint4*)(h + (size_t)n * 32);
        const uint4* s4 = (const uint4*)tmp;
#pragma unroll
        for (int q = 0; q < 4; q++) dst4[q] = s4[q];
    }
}

// -------- fused GAT: own-region in-LDS sort (32 nodes) + wave-per-node agg -----------
// One block (256 thr, 4 waves) per sub-bucket; reads ONLY its own ~8.2 KB stage
// region (pass 1 count, pass 2 scatter — L2-hot re-read), no sibling amplification.
// 17.8 KB LDS -> 8 blocks/CU (100% occupancy). Agg = proven register-accumulator
// wave-per-node loop (8 nodes/wave) from LDS. FINAL fuses 32->1 linear; else fuses
// h2 = relu(out)@W2 + as2/ad2 dots. csr/offs2/k_build/k_h2 all eliminated.
template <bool FINAL>
__global__ __launch_bounds__(256, 8) void k_agg(
    const int* __restrict__ cnt, const int2* __restrict__ stage,
    const __half* __restrict__ h, const float* __restrict__ as_,
    const float* __restrict__ ad_, const float* __restrict__ We,
    const float* __restrict__ ae, const float* __restrict__ bias,
    const float* __restrict__ W2, const float* __restrict__ avs2,
    const float* __restrict__ avd2, __half* __restrict__ hout,
    float* __restrict__ as2, float* __restrict__ ad2,
    const float* __restrict__ lw, const float* __restrict__ lb,
    float* __restrict__ out) {
    __shared__ int2 ebuf[SUBN];         // 10.5 KB node-sorted edges (32 nodes)
    __shared__ int2 xb[4][64];          // per-wave phase buffer
    __shared__ float w2s[1024];         // W2 (layer-1 variant only)
    __shared__ float xrow[4][32];       // per-wave relu'd output row
    __shared__ int ldeg[32];
    __shared__ float esum[32];
    __shared__ int starts[32];
    __shared__ int lcur[32];
    __shared__ int cnts[32];
    __shared__ float means[32];
    int t = threadIdx.x;
    int s = blockIdx.x;                 // sub-bucket id, 0..3124
    int nbase = s * SBN;                // NN = 3125*32 exactly
    int lane = t & 63;
    int wid = t >> 6;                   // wave 0..3
    int g = lane >> 4;                  // 4 edge-slots
    int cp = (lane & 15) * 2;           // comp pair
    int comp = lane & 31;
    // edge-path constant ce = sum_k We[k]*ae[k]
    float ce = We[comp] * ae[comp];
#pragma unroll
    for (int off = 1; off < 32; off <<= 1) ce += __shfl_xor(ce, off);

    // ---------------- count (pass 1 over own region) ----------------
    if (t < 32) { ldeg[t] = 0; esum[t] = 0.f; }
    if (!FINAL)
        for (int i = t; i < 1024; i += 256) w2s[i] = W2[i];
    __syncthreads();
    int c = min(cnt[s], CAPS);
    const int2* ep = stage + (size_t)s * CAPS;
    for (int i = t; i < c; i += 256) {
        int2 e = ep[i];
        int dl = (e.x >> 17) & 31;
        atomicAdd(&ldeg[dl], 1);
        atomicAdd(&esum[dl], __int_as_float(e.y));
    }
    __syncthreads();
    // ---------------- 1-wave shfl scan over 32 nodes ----------------
    if (t < 64) {
        int l = lane;
        int dv = (l < 32) ? ldeg[l] + 1 : 0;        // +1 self-loop slot
        int v = dv;
#pragma unroll
        for (int off = 1; off < 32; off <<= 1) {
            int x = __shfl_up(v, off);
            if (lane >= off) v += x;
        }
        if (l < 32) {
            int st = v - dv;                        // exclusive
            starts[l] = st;
            lcur[l] = st;
            cnts[l] = dv;
            means[l] = esum[l] / fmaxf((float)ldeg[l], 1.0f);
        }
    }
    __syncthreads();
    // ---------------- scatter into LDS (pass 2, L2-hot) ----------------
    for (int i = t; i < c; i += 256) {
        int2 e = ep[i];
        int dl = (e.x >> 17) & 31;
        int pos = atomicAdd(&lcur[dl], 1);
        if (pos < SUBN) ebuf[pos] = make_int2(e.x & 0x1FFFF, e.y);
    }
    __syncthreads();
    if (t < 32) {                                   // self-loop edge, attr = mean
        int p = lcur[t];
        if (p < SUBN) ebuf[p] = make_int2(nbase + t, __float_as_int(means[t]));
    }
    __syncthreads();

    // ---------------- wave-per-node aggregation (register accumulators) -------------
    for (int i2 = 0; i2 < 8; i2++) {
        int n = wid * 8 + i2;                       // wave-uniform
        int gn = nbase + n;
        int base2 = starts[n];
        int cn = cnts[n];
        if (base2 >= SUBN) cn = 0;
        else if (cn > SUBN - base2) cn = SUBN - base2;   // overflow guard (never hit)
        float adn = ad_[gn];
        float2 acc0 = {0.f, 0.f}, acc1 = {0.f, 0.f}, acc2 = {0.f, 0.f}, acc3 = {0.f, 0.f};
        float exs = 0.f;
        for (int cb = 0; cb < cn; cb += 64) {
            // phase A: one edge per lane, exp once
            int idx = cb + lane;
            bool val = idx < cn;
            int2 e = ebuf[base2 + (val ? idx : 0)];
            float a = as_[e.x] + adn + ce * __int_as_float(e.y);
            a = (a >= 0.f) ? a : SLOPE * a;
            float ex = val ? __expf(a) : 0.f;
            exs += ex;
            xb[wid][lane] = make_int2(e.x << 5, __float_as_int(ex));
            // phase B: 16 edges/iter across 4 slots, 4 half2 h-loads in flight
            int m = min(cn - cb, 64);
            for (int j = 0; j < m; j += 16) {
                int2 p0 = xb[wid][j + g];
                int2 p1 = xb[wid][j + 4 + g];
                int2 p2 = xb[wid][j + 8 + g];
                int2 p3 = xb[wid][j + 12 + g];
                float2 h0 = __half22float2(*(const __half2*)(h + p0.x + cp));
                float2 h1 = __half22float2(*(const __half2*)(h + p1.x + cp));
                float2 h2 = __half22float2(*(const __half2*)(h + p2.x + cp));
                float2 h3 = __half22float2(*(const __half2*)(h + p3.x + cp));
                float w0 = __int_as_float(p0.y), w1 = __int_as_float(p1.y);
                float w2 = __int_as_float(p2.y), w3 = __int_as_float(p3.y);
                acc0.x += w0 * h0.x; acc0.y += w0 * h0.y;
                acc1.x += w1 * h1.x; acc1.y += w1 * h1.y;
                acc2.x += w2 * h2.x; acc2.y += w2 * h2.y;
                acc3.x += w3 * h3.x; acc3.y += w3 * h3.y;
            }
        }
        float2 acc;
        acc.x = (acc0.x + acc1.x) + (acc2.x + acc3.x);
        acc.y = (acc0.y + acc1.y) + (acc2.y + acc3.y);
        acc.x += __shfl_xor(acc.x, 16); acc.y += __shfl_xor(acc.y, 16);
        acc.x += __shfl_xor(acc.x, 32); acc.y += __shfl_xor(acc.y, 32);
#pragma unroll
        for (int off = 1; off < 64; off <<= 1) exs += __shfl_xor(exs, off);
        float inv = 1.0f / (exs + 1e-16f);
        float ox = acc.x * inv + bias[cp];
        float oy = acc.y * inv + bias[cp + 1];
        if (FINAL) {
            float y = ox * lw[cp] + oy * lw[cp + 1];     // fused final linear 32 -> 1
#pragma unroll
            for (int off = 1; off < 16; off <<= 1) y += __shfl_xor(y, off);
            if (lane == 0) out[gn] = y + lb[0];
        } else {
            ox = fmaxf(ox, 0.f);
            oy = fmaxf(oy, 0.f);
            if (lane < 16) { xrow[wid][cp] = ox; xrow[wid][cp + 1] = oy; }
            // fused h2 = relu(x) @ W2 (same-wave LDS write->read, lockstep safe)
            float hx = 0.f, hy = 0.f;
#pragma unroll
            for (int k = 0; k < 32; k++) {
                float xk = xrow[wid][k];
                hx += xk * w2s[k * 32 + cp];
                hy += xk * w2s[k * 32 + cp + 1];
            }
            float ps = hx * avs2[cp] + hy * avs2[cp + 1];
            float pd = hx * avd2[cp] + hy * avd2[cp + 1];
#pragma unroll
            for (int off = 1; off < 16; off <<= 1) {
                ps += __shfl_xor(ps, off);
                pd += __shfl_xor(pd, off);
            }
            if (lane == 0) { as2[gn] = ps; ad2[gn] = pd; }
            if (lane < 16)
                *(__half2*)(hout + ((size_t)gn << 5) + cp) = __floats2half2_rn(hx, hy);
        }
    }
}

// ---------------- launch ----------------

extern "C" void kernel_launch(void* const* d_in, const int* in_sizes, int n_in,
                              void* d_out, int out_size, void* d_ws, size_t ws_size,
                              hipStream_t stream) {
    const int* x_ids = (const int*)d_in[0];
    const float* x_feat = (const float*)d_in[1];
    const int* src = (const int*)d_in[2];
    const int* dst = (const int*)d_in[3];
    const float* eattr = (const float*)d_in[4];
    const float* emb = (const float*)d_in[5];
    const float* W1 = (const float*)d_in[6];
    const float* a_s1 = (const float*)d_in[7];
    const float* a_d1 = (const float*)d_in[8];
    const float* We1 = (const float*)d_in[9];
    const float* a_e1 = (const float*)d_in[10];
    const float* b1 = (const float*)d_in[11];
    const float* W2 = (const float*)d_in[12];
    const float* a_s2 = (const float*)d_in[13];
    const float* a_d2 = (const float*)d_in[14];
    const float* We2 = (const float*)d_in[15];
    const float* a_e2 = (const float*)d_in[16];
    const float* b2 = (const float*)d_in[17];
    const float* lin_w = (const float*)d_in[18];
    const float* lin_b = (const float*)d_in[19];

    char* p = (char*)d_ws;
    auto alloc = [&](size_t bytes) {
        void* r = (void*)p;
        p += (bytes + 255) & ~(size_t)255;
        return r;
    };
    int* cnt = (int*)alloc(NSB * 4);
    float* asb1 = (float*)alloc(NN * 4);
    float* adb1 = (float*)alloc(NN * 4);
    float* asb2 = (float*)alloc(NN * 4);
    float* adb2 = (float*)alloc(NN * 4);
    __half* h1 = (__half*)alloc((size_t)NN * 32 * 2);    // 6.4 MB fp16
    __half* h2 = (__half*)alloc((size_t)NN * 32 * 2);    // 6.4 MB fp16
    int2* stage = (int2*)alloc((size_t)NSB * CAPS * 8);  // 33.6 MB, lives thru both layers
    (void)ws_size; (void)in_sizes; (void)n_in; (void)out_size;

    hipMemsetAsync(cnt, 0, NSB * 4, stream);

    k_fat<<<NBB + NBT, 256, 0, stream>>>(src, dst, eattr, cnt, stage,
                                         x_ids, x_feat, emb, W1, a_s1, a_d1,
                                         h1, asb1, adb1);
    k_agg<false><<<NSB, 256, 0, stream>>>(cnt, stage, h1, asb1, adb1,
                                          We1, a_e1, b1,
                                          W2, a_s2, a_d2, h2, asb2, adb2,
                                          nullptr, nullptr, nullptr);
    k_agg<true><<<NSB, 256, 0, stream>>>(cnt, stage, h2, asb2, adb2,
                                         We2, a_e2, b2,
                                         nullptr, nullptr, nullptr,
                                         nullptr, nullptr, nullptr,
                                         lin_w, lin_b, (float*)d_out);
}

// Round 5
// 312.214 us; speedup vs baseline: 1.7552x; 1.7552x over previous
//
#include <hip/hip_runtime.h>
#include <hip/hip_fp16.h>

#define NN 100000
#define EE 3200000
#define SLOPE 0.2f

#define BKN 128                              // dst-nodes per coarse bucket
constexpr int NBK = (NN + BKN - 1) / BKN;    // 782 buckets
#define CAP 4544                             // coarse bucket cap: mean 4096 + 7 sigma
#define EPB 4096                             // edges per bucket-sort block
constexpr int NBB = (EE + EPB - 1) / EPB;    // 782 sort blocks
constexpr int NBT = (NN + 255) / 256;        // 391 node blocks
#define SUBN 1344                            // edge cap per 32-node sub-bucket (+9 sigma)
constexpr int NSB = NBK * 4;                 // 3128 sub-buckets = 8 XCDs * 391 exactly

// ------------- fat kernel: bucket counting-sort (blocks 0..NBB) + h1 (rest) -----------
// record = {src | (dst&127)<<17, edge_attr}; reservation atomic doubles as bucket count
__global__ void k_fat(const int* __restrict__ src, const int* __restrict__ dst,
                      const float* __restrict__ ea, int* __restrict__ cnt,
                      int2* __restrict__ stage,
                      const int* __restrict__ ids, const float* __restrict__ feat,
                      const float* __restrict__ emb, const float* __restrict__ W,
                      const float* __restrict__ avs, const float* __restrict__ avd,
                      __half* __restrict__ h, float* __restrict__ as_,
                      float* __restrict__ ad_) {
    __shared__ int hst[NBK];
    __shared__ int scl[NBK];
    __shared__ int gdel[NBK];
    __shared__ int aux[256];
    __shared__ int2 rec[EPB];
    __shared__ int addr[EPB];
    int t = threadIdx.x;
    if (blockIdx.x < NBB) {
        // ---------- bucket counting sort ----------
        int base = blockIdx.x * EPB;
        int nedge = min(EPB, EE - base);
        for (int i = t; i < NBK; i += 256) hst[i] = 0;
        __syncthreads();
        int ds[16], ss[16]; float es[16];
#pragma unroll
        for (int j = 0; j < 16; j++) {
            int e = base + j * 256 + t;
            bool v = e < EE;
            ds[j] = v ? dst[e] : -1;
            ss[j] = v ? src[e] : 0;
            es[j] = v ? ea[e] : 0.f;
            if (v) atomicAdd(&hst[ds[j] >> 7], 1);
        }
        __syncthreads();
        int i0 = t * 4;
        int v0 = (i0 + 0 < NBK) ? hst[i0 + 0] : 0;
        int v1 = (i0 + 1 < NBK) ? hst[i0 + 1] : 0;
        int v2 = (i0 + 2 < NBK) ? hst[i0 + 2] : 0;
        int v3 = (i0 + 3 < NBK) ? hst[i0 + 3] : 0;
        int tsum = v0 + v1 + v2 + v3;
        aux[t] = tsum;
        __syncthreads();
        for (int off = 1; off < 256; off <<= 1) {
            int x = (t >= off) ? aux[t - off] : 0;
            __syncthreads();
            aux[t] += x;
            __syncthreads();
        }
        int ex = aux[t] - tsum;
        if (i0 + 0 < NBK) scl[i0 + 0] = ex;
        if (i0 + 1 < NBK) scl[i0 + 1] = ex + v0;
        if (i0 + 2 < NBK) scl[i0 + 2] = ex + v0 + v1;
        if (i0 + 3 < NBK) scl[i0 + 3] = ex + v0 + v1 + v2;
        __syncthreads();
        for (int i = t; i < NBK; i += 256) {
            int hh = hst[i];
            int g = hh ? atomicAdd(&cnt[i], hh) : 0;
            gdel[i] = (g + i * CAP) - scl[i];
        }
        __syncthreads();
#pragma unroll
        for (int j = 0; j < 16; j++) {
            if (ds[j] >= 0) {
                int bk = ds[j] >> 7;
                int pos = atomicAdd(&scl[bk], 1);
                int gpos = pos + gdel[bk];
                rec[pos] = make_int2(ss[j] | ((ds[j] & 127) << 17), __float_as_int(es[j]));
                addr[pos] = (gpos - bk * CAP < CAP) ? gpos : -1;
            }
        }
        __syncthreads();
        for (int i = t; i < nedge; i += 256) {
            int a = addr[i];
            if (a >= 0) stage[a] = rec[i];
        }
    } else {
        // ---------- h1: x=concat(emb,feat); h=x@W1 (stored fp16); as/ad dots fp32 -----
        int n = (blockIdx.x - NBB) * 256 + t;
        if (n >= NN) return;
        float hv[32];
#pragma unroll
        for (int j = 0; j < 32; j++) hv[j] = 0.f;
        int id = ids[n];
        const float4* e4 = (const float4*)(emb + (size_t)id * 16);
#pragma unroll
        for (int k4 = 0; k4 < 4; k4++) {
            float4 xv = e4[k4];
            const float* wr = W + k4 * 4 * 32;
#pragma unroll
            for (int j = 0; j < 32; j++)
                hv[j] += xv.x * wr[j] + xv.y * wr[32 + j] + xv.z * wr[64 + j] + xv.w * wr[96 + j];
        }
        float f = feat[n];
#pragma unroll
        for (int j = 0; j < 32; j++) hv[j] += f * W[16 * 32 + j];
        float s = 0.f, d = 0.f;
#pragma unroll
        for (int j = 0; j < 32; j++) { s += hv[j] * avs[j]; d += hv[j] * avd[j]; }
        as_[n] = s;
        ad_[n] = d;
        __half2 tmp[16];
#pragma unroll
        for (int q = 0; q < 16; q++) tmp[q] = __floats2half2_rn(hv[2 * q], hv[2 * q + 1]);
        uint4* dst4 = (uint4*)(h + (size_t)n * 32);
        const uint4* s4 = (const uint4*)tmp;
#pragma unroll
        for (int q = 0; q < 4; q++) dst4[q] = s4[q];
    }
}

// -------- layer 1: sub-bucket in-LDS sort + csr writeback + agg + fused h2 -----------
// XCD-swizzled: b2 = (p&7)*391 + (p>>3) puts the 4 sibling blocks of each coarse
// bucket on ONE XCD (runtime: block p -> XCD p%8), so siblings' filter passes hit
// the same L2 (R3's 104 MB stage amplification -> ~28 MB). After the LDS sort, the
// node-contiguous edge list is written to global csr/offs2 so layer 2 never sorts.
// Agg = proven register-accumulator wave-per-node loop; epilogue fuses h2/as2/ad2.
__global__ __launch_bounds__(256, 8) void k_l1(
    const int* __restrict__ cnt, const int2* __restrict__ stage,
    const __half* __restrict__ h, const float* __restrict__ as_,
    const float* __restrict__ ad_, const float* __restrict__ We,
    const float* __restrict__ ae, const float* __restrict__ bias,
    const float* __restrict__ W2, const float* __restrict__ avs2,
    const float* __restrict__ avd2, __half* __restrict__ hout,
    float* __restrict__ as2, float* __restrict__ ad2,
    int2* __restrict__ csr, int2* __restrict__ offs2) {
    __shared__ int2 ebuf[SUBN];         // 10.5 KB node-sorted edges (32 nodes)
    __shared__ int2 xb[4][64];          // per-wave phase buffer
    __shared__ float w2s[1024];         // W2
    __shared__ float xrow[4][32];       // per-wave relu'd output row
    __shared__ int ldeg[32];
    __shared__ float esum[32];
    __shared__ int starts[32];
    __shared__ int lcur[32];
    __shared__ int cnts[32];
    __shared__ float means[32];
    int t = threadIdx.x;
    int p = blockIdx.x;                 // 3128 = 8*391 exactly
    int b2 = (p & 7) * 391 + (p >> 3);  // sibling-grouping XCD swizzle (bijective)
    int b = b2 >> 2, q = b2 & 3;
    int nbase = b * BKN + q * 32;
    int npb = min(32, NN - nbase);
    if (npb <= 0) return;
    int lane = t & 63;
    int wid = t >> 6;                   // wave 0..3
    int g = lane >> 4;                  // 4 edge-slots
    int cp = (lane & 15) * 2;           // comp pair
    int comp = lane & 31;
    // edge-path constant ce = sum_k We[k]*ae[k]
    float ce = We[comp] * ae[comp];
#pragma unroll
    for (int off = 1; off < 32; off <<= 1) ce += __shfl_xor(ce, off);

    // ---------------- filter + count (pass 1; 1st sibling misses, rest L2-hit) ------
    if (t < 32) { ldeg[t] = 0; esum[t] = 0.f; }
    for (int i = t; i < 1024; i += 256) w2s[i] = W2[i];
    __syncthreads();
    int c = min(cnt[b], CAP);
    const int2* ep = stage + (size_t)b * CAP;
    for (int i = t; i < c; i += 256) {
        int2 e = ep[i];
        int dl = (e.x >> 17) & 127;
        if ((dl >> 5) == q) {
            atomicAdd(&ldeg[dl & 31], 1);
            atomicAdd(&esum[dl & 31], __int_as_float(e.y));
        }
    }
    __syncthreads();
    // ---------------- 1-wave shfl scan over 32 nodes ----------------
    if (t < 64) {
        int l = lane;
        int dv = (l < npb) ? ldeg[l] + 1 : 0;       // +1 self-loop slot
        int v = dv;
#pragma unroll
        for (int off = 1; off < 32; off <<= 1) {
            int x = __shfl_up(v, off);
            if (lane >= off) v += x;
        }
        if (l < 32) {
            int st = v - dv;                        // exclusive
            starts[l] = st;
            lcur[l] = st;
            cnts[l] = dv;
            means[l] = esum[l] / fmaxf((float)ldeg[l], 1.0f);
        }
    }
    __syncthreads();
    // ---------------- scatter into LDS (pass 2, L2-hot) ----------------
    for (int i = t; i < c; i += 256) {
        int2 e = ep[i];
        int dl = (e.x >> 17) & 127;
        if ((dl >> 5) == q) {
            int pos = atomicAdd(&lcur[dl & 31], 1);
            if (pos < SUBN) ebuf[pos] = make_int2(e.x & 0x1FFFF, e.y);
        }
    }
    __syncthreads();
    if (t < npb) {                                  // self-loop edge, attr = mean
        int pp = lcur[t];
        if (pp < SUBN) ebuf[pp] = make_int2(nbase + t, __float_as_int(means[t]));
    }
    __syncthreads();
    // ---------------- csr/offs2 writeback (layer 2 consumes, no re-sort) ------------
    int tot = min(starts[31] + cnts[31], SUBN);
    int2* cw = csr + (size_t)b2 * SUBN;
    for (int i = t; i < tot; i += 256) cw[i] = ebuf[i];
    if (t < npb) {
        int st = starts[t];
        int cn = cnts[t];
        if (st >= SUBN) { st = 0; cn = 0; }
        else if (cn > SUBN - st) cn = SUBN - st;
        offs2[nbase + t] = make_int2(b2 * SUBN + st, cn);
    }

    // ---------------- wave-per-node aggregation (register accumulators) -------------
    for (int i2 = 0; i2 < 8; i2++) {
        int n = wid * 8 + i2;                       // wave-uniform
        if (n >= npb) break;
        int gn = nbase + n;
        int base2 = starts[n];
        int cn = cnts[n];
        if (base2 >= SUBN) cn = 0;
        else if (cn > SUBN - base2) cn = SUBN - base2;   // overflow guard (never hit)
        float adn = ad_[gn];
        float2 acc0 = {0.f, 0.f}, acc1 = {0.f, 0.f}, acc2 = {0.f, 0.f}, acc3 = {0.f, 0.f};
        float exs = 0.f;
        for (int cb = 0; cb < cn; cb += 64) {
            // phase A: one edge per lane, exp once
            int idx = cb + lane;
            bool val = idx < cn;
            int2 e = ebuf[base2 + (val ? idx : 0)];
            float a = as_[e.x] + adn + ce * __int_as_float(e.y);
            a = (a >= 0.f) ? a : SLOPE * a;
            float ex = val ? __expf(a) : 0.f;
            exs += ex;
            xb[wid][lane] = make_int2(e.x << 5, __float_as_int(ex));
            // phase B: 16 edges/iter across 4 slots, 4 half2 h-loads in flight
            int m = min(cn - cb, 64);
            for (int j = 0; j < m; j += 16) {
                int2 p0 = xb[wid][j + g];
                int2 p1 = xb[wid][j + 4 + g];
                int2 p2 = xb[wid][j + 8 + g];
                int2 p3 = xb[wid][j + 12 + g];
                float2 h0 = __half22float2(*(const __half2*)(h + p0.x + cp));
                float2 h1 = __half22float2(*(const __half2*)(h + p1.x + cp));
                float2 h2 = __half22float2(*(const __half2*)(h + p2.x + cp));
                float2 h3 = __half22float2(*(const __half2*)(h + p3.x + cp));
                float w0 = __int_as_float(p0.y), w1 = __int_as_float(p1.y);
                float w2 = __int_as_float(p2.y), w3 = __int_as_float(p3.y);
                acc0.x += w0 * h0.x; acc0.y += w0 * h0.y;
                acc1.x += w1 * h1.x; acc1.y += w1 * h1.y;
                acc2.x += w2 * h2.x; acc2.y += w2 * h2.y;
                acc3.x += w3 * h3.x; acc3.y += w3 * h3.y;
            }
        }
        float2 acc;
        acc.x = (acc0.x + acc1.x) + (acc2.x + acc3.x);
        acc.y = (acc0.y + acc1.y) + (acc2.y + acc3.y);
        acc.x += __shfl_xor(acc.x, 16); acc.y += __shfl_xor(acc.y, 16);
        acc.x += __shfl_xor(acc.x, 32); acc.y += __shfl_xor(acc.y, 32);
#pragma unroll
        for (int off = 1; off < 64; off <<= 1) exs += __shfl_xor(exs, off);
        float inv = 1.0f / (exs + 1e-16f);
        float ox = acc.x * inv + bias[cp];
        float oy = acc.y * inv + bias[cp + 1];
        ox = fmaxf(ox, 0.f);
        oy = fmaxf(oy, 0.f);
        if (lane < 16) { xrow[wid][cp] = ox; xrow[wid][cp + 1] = oy; }
        // fused h2 = relu(x) @ W2 (same-wave LDS write->read, lockstep safe)
        float hx = 0.f, hy = 0.f;
#pragma unroll
        for (int k = 0; k < 32; k++) {
            float xk = xrow[wid][k];
            hx += xk * w2s[k * 32 + cp];
            hy += xk * w2s[k * 32 + cp + 1];
        }
        float ps = hx * avs2[cp] + hy * avs2[cp + 1];
        float pd = hx * avd2[cp] + hy * avd2[cp + 1];
#pragma unroll
        for (int off = 1; off < 16; off <<= 1) {
            ps += __shfl_xor(ps, off);
            pd += __shfl_xor(pd, off);
        }
        if (lane == 0) { as2[gn] = ps; ad2[gn] = pd; }
        if (lane < 16)
            *(__half2*)(hout + ((size_t)gn << 5) + cp) = __floats2half2_rn(hx, hy);
    }
}

// -------- layer 2: R0's proven wave-per-node k_gat (csr-reading) + fused linear ------
__global__ void k_gat(const int2* __restrict__ offs2, const int2* __restrict__ csr,
                      const __half* __restrict__ h, const float* __restrict__ as_,
                      const float* __restrict__ ad_,
                      const float* __restrict__ We, const float* __restrict__ ae,
                      const float* __restrict__ bias,
                      const float* __restrict__ lw, const float* __restrict__ lb,
                      float* __restrict__ out) {
    __shared__ int2 xb[4][64];
    int wid = threadIdx.x >> 6;
    int node = blockIdx.x * 4 + wid;           // NN = 25000*4 exactly
    int lane = threadIdx.x & 63;
    int comp = lane & 31;
    int cp = (lane & 15) * 2;                  // comp pair for phase B
    int slot4 = lane >> 4;                     // 0..3
    float c = We[comp] * ae[comp];
#pragma unroll
    for (int off = 1; off < 32; off <<= 1) c += __shfl_xor(c, off);
    int2 oo = offs2[node];
    int base = oo.x;
    int cnt = oo.y;                            // >= 1 (self-loop)
    float adn = ad_[node];
    float2 acc0 = {0.f, 0.f}, acc1 = {0.f, 0.f}, acc2 = {0.f, 0.f}, acc3 = {0.f, 0.f};
    float exs = 0.f;
    for (int cb = 0; cb < cnt; cb += 64) {
        int idx = cb + lane;
        bool val = idx < cnt;
        int2 e = csr[base + (val ? idx : 0)];
        float a = as_[e.x] + adn + c * __int_as_float(e.y);
        a = (a >= 0.f) ? a : SLOPE * a;
        float ex = val ? __expf(a) : 0.f;
        exs += ex;
        xb[wid][lane] = make_int2(e.x << 5, __float_as_int(ex));
        int m = min(cnt - cb, 64);
        for (int j = 0; j < m; j += 16) {
            int2 p0 = xb[wid][j + slot4];
            int2 p1 = xb[wid][j + 4 + slot4];
            int2 p2 = xb[wid][j + 8 + slot4];
            int2 p3 = xb[wid][j + 12 + slot4];
            float2 h0 = __half22float2(*(const __half2*)(h + p0.x + cp));
            float2 h1 = __half22float2(*(const __half2*)(h + p1.x + cp));
            float2 h2 = __half22float2(*(const __half2*)(h + p2.x + cp));
            float2 h3 = __half22float2(*(const __half2*)(h + p3.x + cp));
            float w0 = __int_as_float(p0.y), w1 = __int_as_float(p1.y);
            float w2 = __int_as_float(p2.y), w3 = __int_as_float(p3.y);
            acc0.x += w0 * h0.x; acc0.y += w0 * h0.y;
            acc1.x += w1 * h1.x; acc1.y += w1 * h1.y;
            acc2.x += w2 * h2.x; acc2.y += w2 * h2.y;
            acc3.x += w3 * h3.x; acc3.y += w3 * h3.y;
        }
    }
    float2 acc;
    acc.x = (acc0.x + acc1.x) + (acc2.x + acc3.x);
    acc.y = (acc0.y + acc1.y) + (acc2.y + acc3.y);
    acc.x += __shfl_xor(acc.x, 16); acc.y += __shfl_xor(acc.y, 16);
    acc.x += __shfl_xor(acc.x, 32); acc.y += __shfl_xor(acc.y, 32);
#pragma unroll
    for (int off = 1; off < 64; off <<= 1) exs += __shfl_xor(exs, off);
    float inv = 1.0f / (exs + 1e-16f);
    float ox = acc.x * inv + bias[cp];
    float oy = acc.y * inv + bias[cp + 1];
    float y = ox * lw[cp] + oy * lw[cp + 1];   // fused final linear 32 -> 1
#pragma unroll
    for (int off = 1; off < 16; off <<= 1) y += __shfl_xor(y, off);
    if (lane == 0) out[node] = y + lb[0];
}

// ---------------- launch ----------------

extern "C" void kernel_launch(void* const* d_in, const int* in_sizes, int n_in,
                              void* d_out, int out_size, void* d_ws, size_t ws_size,
                              hipStream_t stream) {
    const int* x_ids = (const int*)d_in[0];
    const float* x_feat = (const float*)d_in[1];
    const int* src = (const int*)d_in[2];
    const int* dst = (const int*)d_in[3];
    const float* eattr = (const float*)d_in[4];
    const float* emb = (const float*)d_in[5];
    const float* W1 = (const float*)d_in[6];
    const float* a_s1 = (const float*)d_in[7];
    const float* a_d1 = (const float*)d_in[8];
    const float* We1 = (const float*)d_in[9];
    const float* a_e1 = (const float*)d_in[10];
    const float* b1 = (const float*)d_in[11];
    const float* W2 = (const float*)d_in[12];
    const float* a_s2 = (const float*)d_in[13];
    const float* a_d2 = (const float*)d_in[14];
    const float* We2 = (const float*)d_in[15];
    const float* a_e2 = (const float*)d_in[16];
    const float* b2 = (const float*)d_in[17];
    const float* lin_w = (const float*)d_in[18];
    const float* lin_b = (const float*)d_in[19];

    char* p = (char*)d_ws;
    auto alloc = [&](size_t bytes) {
        void* r = (void*)p;
        p += (bytes + 255) & ~(size_t)255;
        return r;
    };
    int* cnt = (int*)alloc(NBK * 4);
    int2* offs2 = (int2*)alloc((size_t)NN * 8);
    float* asb1 = (float*)alloc(NN * 4);
    float* adb1 = (float*)alloc(NN * 4);
    float* asb2 = (float*)alloc(NN * 4);
    float* adb2 = (float*)alloc(NN * 4);
    __half* h1 = (__half*)alloc((size_t)NN * 32 * 2);    // 6.4 MB fp16
    __half* h2 = (__half*)alloc((size_t)NN * 32 * 2);    // 6.4 MB fp16
    int2* csr = (int2*)alloc((size_t)NSB * SUBN * 8);    // 33.6 MB node-sorted edges
    int2* stage = (int2*)alloc((size_t)NBK * CAP * 8);   // 28.4 MB (dead after k_l1)
    (void)ws_size; (void)in_sizes; (void)n_in; (void)out_size;

    hipMemsetAsync(cnt, 0, NBK * 4, stream);

    k_fat<<<NBB + NBT, 256, 0, stream>>>(src, dst, eattr, cnt, stage,
                                         x_ids, x_feat, emb, W1, a_s1, a_d1,
                                         h1, asb1, adb1);
    k_l1<<<NSB, 256, 0, stream>>>(cnt, stage, h1, asb1, adb1,
                                  We1, a_e1, b1,
                                  W2, a_s2, a_d2, h2, asb2, adb2,
                                  csr, offs2);
    k_gat<<<(NN + 3) / 4, 256, 0, stream>>>(offs2, csr, h2, asb2, adb2,
                                            We2, a_e2, b2,
                                            lin_w, lin_b, (float*)d_out);
}